// Round 1
// baseline (42938.721 us; speedup 1.0000x reference)
//
#include <hip/hip_runtime.h>
#include <hip/hip_cooperative_groups.h>

namespace cg = cooperative_groups;

constexpr int SEQ = 4096;   // timesteps
constexpr int IN  = 512;    // input size
constexpr int RS  = 2048;   // reservoir size
constexpr int GB  = 64;     // blocks in scan kernel
constexpr int BT  = 1024;   // threads per block in scan kernel
constexpr float INV_SQRT = 0.022097086912079612f; // 1/sqrt(2048)

// ---------------------------------------------------------------------------
// Phase 1: pre = X @ W_in^T, written to out rows 1..SEQ (in-place scan buffer)
// C[m][n] = sum_k A[m][k] * B[n][k];  store at out[(m+1)*RS + n]
// 64x64 tile, 256 threads, 4x4 per-thread microtile, K-panel = 16.
// ---------------------------------------------------------------------------
__global__ __launch_bounds__(256)
void gemm_pre_kernel(const float* __restrict__ A, const float* __restrict__ B,
                     float* __restrict__ out) {
    __shared__ float As[64][17];
    __shared__ float Bs[64][17];
    const int tid = threadIdx.x;
    const int tx = tid & 15, ty = tid >> 4;
    const int m0 = blockIdx.x * 64, n0 = blockIdx.y * 64;
    const int lr = tid >> 2;          // 0..63: row within tile (for staging)
    const int lk = (tid & 3) * 4;     // 0,4,8,12: k within panel (for staging)
    float acc[4][4] = {};
    for (int k0 = 0; k0 < IN; k0 += 16) {
        const float4 av = *(const float4*)&A[(size_t)(m0 + lr) * IN + k0 + lk];
        const float4 bv = *(const float4*)&B[(size_t)(n0 + lr) * IN + k0 + lk];
        __syncthreads();
        As[lr][lk + 0] = av.x; As[lr][lk + 1] = av.y;
        As[lr][lk + 2] = av.z; As[lr][lk + 3] = av.w;
        Bs[lr][lk + 0] = bv.x; Bs[lr][lk + 1] = bv.y;
        Bs[lr][lk + 2] = bv.z; Bs[lr][lk + 3] = bv.w;
        __syncthreads();
#pragma unroll
        for (int k = 0; k < 16; ++k) {
            float a[4], b[4];
#pragma unroll
            for (int i = 0; i < 4; ++i) a[i] = As[ty * 4 + i][k];
#pragma unroll
            for (int j = 0; j < 4; ++j) b[j] = Bs[tx * 4 + j][k];
#pragma unroll
            for (int i = 0; i < 4; ++i)
#pragma unroll
                for (int j = 0; j < 4; ++j) acc[i][j] += a[i] * b[j];
        }
    }
#pragma unroll
    for (int i = 0; i < 4; ++i) {
        float4 v = make_float4(acc[i][0], acc[i][1], acc[i][2], acc[i][3]);
        *(float4*)&out[(size_t)(m0 + ty * 4 + i + 1) * RS + n0 + tx * 4] = v;
    }
}

// ---------------------------------------------------------------------------
// Phase 2: persistent cooperative scan.
//   state_t = tanh(pre_t + W_res @ state_{t-1}) * INV_SQRT
// In-place: out[t+1] holds pre_t on entry to step t, the state on exit.
// 64 blocks x 1024 threads. W_res lives entirely in registers:
//   wave w of block b owns rows r0 = b*32 + 2w and r0+1;
//   lane l holds k = {4l + 256j .. +3}, j = 0..7  -> 64 floats/thread.
// ---------------------------------------------------------------------------
__global__ __launch_bounds__(BT, 1)
void reservoir_scan_kernel(const float* __restrict__ W_res,
                           const float* __restrict__ init,
                           float* __restrict__ out) {
    cg::grid_group grid = cg::this_grid();
    const int bid  = blockIdx.x;
    const int tid  = threadIdx.x;
    const int wave = tid >> 6;
    const int lane = tid & 63;
    const int r0   = bid * 32 + wave * 2;

    const float* wp0 = W_res + (size_t)r0 * RS + lane * 4;
    const float* wp1 = wp0 + RS;
    float4 w0[8], w1[8];
#pragma unroll
    for (int j = 0; j < 8; ++j) {
        w0[j] = *(const float4*)(wp0 + j * 256);
        w1[j] = *(const float4*)(wp1 + j * 256);
    }

    // row 0 of the output = initial state (each block writes its 32-slice)
    if (tid < 32) out[bid * 32 + tid] = init[bid * 32 + tid];
    grid.sync();

    for (int t = 0; t < SEQ; ++t) {
        const float* s = out + (size_t)t * RS + lane * 4;
        float4 sv[8];
#pragma unroll
        for (int j = 0; j < 8; ++j) sv[j] = *(const float4*)(s + j * 256);

        float a0 = 0.f, a1 = 0.f;
#pragma unroll
        for (int j = 0; j < 8; ++j) {
            a0 += w0[j].x * sv[j].x + w0[j].y * sv[j].y
                + w0[j].z * sv[j].z + w0[j].w * sv[j].w;
            a1 += w1[j].x * sv[j].x + w1[j].y * sv[j].y
                + w1[j].z * sv[j].z + w1[j].w * sv[j].w;
        }
#pragma unroll
        for (int off = 32; off > 0; off >>= 1) {
            a0 += __shfl_xor(a0, off);
            a1 += __shfl_xor(a1, off);
        }
        if (lane == 0) {
            float* o = out + (size_t)(t + 1) * RS;
            o[r0]     = tanhf(o[r0]     + a0) * INV_SQRT;
            o[r0 + 1] = tanhf(o[r0 + 1] + a1) * INV_SQRT;
        }
        grid.sync();
    }
}

extern "C" void kernel_launch(void* const* d_in, const int* in_sizes, int n_in,
                              void* d_out, int out_size, void* d_ws, size_t ws_size,
                              hipStream_t stream) {
    const float* x     = (const float*)d_in[0];  // (4096, 512)
    const float* init  = (const float*)d_in[1];  // (2048,)
    const float* W_in  = (const float*)d_in[2];  // (2048, 512)
    const float* W_res = (const float*)d_in[3];  // (2048, 2048)
    float* out = (float*)d_out;                  // (4097, 2048)

    gemm_pre_kernel<<<dim3(SEQ / 64, RS / 64), 256, 0, stream>>>(x, W_in, out);

    void* args[] = { (void*)&W_res, (void*)&init, (void*)&out };
    hipLaunchCooperativeKernel((void*)reservoir_scan_kernel,
                               dim3(GB), dim3(BT), args, 0, stream);
}

// Round 2
// 20976.332 us; speedup vs baseline: 2.0470x; 2.0470x over previous
//
#include <hip/hip_runtime.h>

constexpr int SEQ = 4096;   // timesteps
constexpr int IN  = 512;    // input size
constexpr int RS  = 2048;   // reservoir size
constexpr int GB  = 64;     // blocks in scan kernel
constexpr int BT  = 1024;   // threads per block in scan kernel
constexpr float INV_SQRT = 0.022097086912079612f; // 1/sqrt(2048)

// ---------------------------------------------------------------------------
// Phase 1: pre = X @ W_in^T, written to out rows 1..SEQ (in-place scan buffer)
// ---------------------------------------------------------------------------
__global__ __launch_bounds__(256)
void gemm_pre_kernel(const float* __restrict__ A, const float* __restrict__ B,
                     float* __restrict__ out) {
    __shared__ float As[64][17];
    __shared__ float Bs[64][17];
    const int tid = threadIdx.x;
    const int tx = tid & 15, ty = tid >> 4;
    const int m0 = blockIdx.x * 64, n0 = blockIdx.y * 64;
    const int lr = tid >> 2;
    const int lk = (tid & 3) * 4;
    float acc[4][4] = {};
    for (int k0 = 0; k0 < IN; k0 += 16) {
        const float4 av = *(const float4*)&A[(size_t)(m0 + lr) * IN + k0 + lk];
        const float4 bv = *(const float4*)&B[(size_t)(n0 + lr) * IN + k0 + lk];
        __syncthreads();
        As[lr][lk + 0] = av.x; As[lr][lk + 1] = av.y;
        As[lr][lk + 2] = av.z; As[lr][lk + 3] = av.w;
        Bs[lr][lk + 0] = bv.x; Bs[lr][lk + 1] = bv.y;
        Bs[lr][lk + 2] = bv.z; Bs[lr][lk + 3] = bv.w;
        __syncthreads();
#pragma unroll
        for (int k = 0; k < 16; ++k) {
            float a[4], b[4];
#pragma unroll
            for (int i = 0; i < 4; ++i) a[i] = As[ty * 4 + i][k];
#pragma unroll
            for (int j = 0; j < 4; ++j) b[j] = Bs[tx * 4 + j][k];
#pragma unroll
            for (int i = 0; i < 4; ++i)
#pragma unroll
                for (int j = 0; j < 4; ++j) acc[i][j] += a[i] * b[j];
        }
    }
#pragma unroll
    for (int i = 0; i < 4; ++i) {
        float4 v = make_float4(acc[i][0], acc[i][1], acc[i][2], acc[i][3]);
        *(float4*)&out[(size_t)(m0 + ty * 4 + i + 1) * RS + n0 + tx * 4] = v;
    }
}

// ---------------------------------------------------------------------------
// Lightweight grid barrier: monotonic counter, relaxed agent-scope atomics
// (compile to sc1 ops at the L3 coherence point; NO buffer_wbl2/buffer_inv).
// Ordering: compiler emits s_waitcnt vmcnt(0) before s_barrier, so every
// wave's sc1 state stores are at L3 before tid 0 arrives at the counter.
// ---------------------------------------------------------------------------
__device__ __forceinline__ void grid_bar(unsigned* cnt, unsigned bi) {
    asm volatile("s_waitcnt vmcnt(0)" ::: "memory");
    __syncthreads();
    if (threadIdx.x == 0) {
        __hip_atomic_fetch_add(cnt, 1u, __ATOMIC_RELAXED, __HIP_MEMORY_SCOPE_AGENT);
        while (__hip_atomic_load(cnt, __ATOMIC_RELAXED, __HIP_MEMORY_SCOPE_AGENT)
               < (unsigned)GB * bi) { /* spin */ }
    }
    __syncthreads();
}

// ---------------------------------------------------------------------------
// Phase 2: persistent scan. W_res pinned in registers (64 f32/thread).
// State exchanged through L3 via agent-scope (sc1) loads/stores; each block
// stages the 8 KB state vector into LDS once per step.
// ---------------------------------------------------------------------------
__global__ __launch_bounds__(BT, 4)
void reservoir_scan_kernel(const float* __restrict__ W_res,
                           const float* __restrict__ init,
                           float* __restrict__ out,
                           unsigned* __restrict__ bar_cnt) {
    __shared__ float s_state[RS];
    const int bid  = blockIdx.x;
    const int tid  = threadIdx.x;
    const int wave = tid >> 6;
    const int lane = tid & 63;
    const int r0   = bid * 32 + wave * 2;

    // --- W rows r0, r0+1 into registers; pin so they can't be re-loaded ---
    const float* wp0 = W_res + (size_t)r0 * RS + lane * 4;
    const float* wp1 = wp0 + RS;
    float4 w0[8], w1[8];
#pragma unroll
    for (int j = 0; j < 8; ++j) {
        w0[j] = *(const float4*)(wp0 + j * 256);
        w1[j] = *(const float4*)(wp1 + j * 256);
    }
#pragma unroll
    for (int j = 0; j < 8; ++j) {
        asm volatile("" : "+v"(w0[j].x), "+v"(w0[j].y), "+v"(w0[j].z), "+v"(w0[j].w));
        asm volatile("" : "+v"(w1[j].x), "+v"(w1[j].y), "+v"(w1[j].z), "+v"(w1[j].w));
    }

    // --- row 0 of output = initial state (agent-scope so L3 holds it) ---
    if (tid < 32) {
        __hip_atomic_store(&out[bid * 32 + tid], init[bid * 32 + tid],
                           __ATOMIC_RELAXED, __HIP_MEMORY_SCOPE_AGENT);
    }
    grid_bar(bar_cnt, 1);

    for (int t = 0; t < SEQ; ++t) {
        // --- stage state row t into LDS (sc1 loads -> fresh from L3) ---
        const float* row = out + (size_t)t * RS;
        s_state[tid] = __hip_atomic_load(&row[tid],
                                         __ATOMIC_RELAXED, __HIP_MEMORY_SCOPE_AGENT);
        s_state[tid + 1024] = __hip_atomic_load(&row[tid + 1024],
                                         __ATOMIC_RELAXED, __HIP_MEMORY_SCOPE_AGENT);
        __syncthreads();

        // --- two dot products from registers x LDS ---
        float a0 = 0.f, a1 = 0.f;
#pragma unroll
        for (int j = 0; j < 8; ++j) {
            const float4 sv = *(const float4*)&s_state[lane * 4 + j * 256];
            a0 += w0[j].x * sv.x + w0[j].y * sv.y + w0[j].z * sv.z + w0[j].w * sv.w;
            a1 += w1[j].x * sv.x + w1[j].y * sv.y + w1[j].z * sv.z + w1[j].w * sv.w;
        }
#pragma unroll
        for (int off = 32; off > 0; off >>= 1) {
            a0 += __shfl_xor(a0, off);
            a1 += __shfl_xor(a1, off);
        }

        // --- finish: u = pre + a; state = tanh(u)/sqrt(RS); in-place ---
        if (lane < 2) {
            float a = lane ? a1 : a0;
            float* o = out + (size_t)(t + 1) * RS + r0 + lane;
            float pre = __hip_atomic_load(o, __ATOMIC_RELAXED, __HIP_MEMORY_SCOPE_AGENT);
            __hip_atomic_store(o, tanhf(pre + a) * INV_SQRT,
                               __ATOMIC_RELAXED, __HIP_MEMORY_SCOPE_AGENT);
        }
        grid_bar(bar_cnt, (unsigned)(t + 2));
    }
}

extern "C" void kernel_launch(void* const* d_in, const int* in_sizes, int n_in,
                              void* d_out, int out_size, void* d_ws, size_t ws_size,
                              hipStream_t stream) {
    const float* x     = (const float*)d_in[0];  // (4096, 512)
    const float* init  = (const float*)d_in[1];  // (2048,)
    const float* W_in  = (const float*)d_in[2];  // (2048, 512)
    const float* W_res = (const float*)d_in[3];  // (2048, 2048)
    float* out = (float*)d_out;                  // (4097, 2048)
    unsigned* bar_cnt = (unsigned*)d_ws;

    hipMemsetAsync(d_ws, 0, 64, stream);
    gemm_pre_kernel<<<dim3(SEQ / 64, RS / 64), 256, 0, stream>>>(x, W_in, out);

    void* args[] = { (void*)&W_res, (void*)&init, (void*)&out, (void*)&bar_cnt };
    hipLaunchCooperativeKernel((void*)reservoir_scan_kernel,
                               dim3(GB), dim3(BT), args, 0, stream);
}

// Round 3
// 8383.286 us; speedup vs baseline: 5.1219x; 2.5022x over previous
//
#include <hip/hip_runtime.h>

constexpr int SEQ  = 4096;   // timesteps
constexpr int IN   = 512;    // input size
constexpr int RS   = 2048;   // reservoir size
constexpr int GB   = 64;     // blocks in scan kernel
constexpr int BT   = 1024;   // threads per block in scan kernel
constexpr int RING = 8;      // ring depth (epochs); skew bound <= 1, 8 is safe
constexpr float INV_SQRT = 0.022097086912079612f; // 1/sqrt(2048)

// ---------------------------------------------------------------------------
// Phase 1: pre = X @ W_in^T, written to out rows 1..SEQ (in-place scan buffer)
// ---------------------------------------------------------------------------
__global__ __launch_bounds__(256)
void gemm_pre_kernel(const float* __restrict__ A, const float* __restrict__ B,
                     float* __restrict__ out) {
    __shared__ float As[64][17];
    __shared__ float Bs[64][17];
    const int tid = threadIdx.x;
    const int tx = tid & 15, ty = tid >> 4;
    const int m0 = blockIdx.x * 64, n0 = blockIdx.y * 64;
    const int lr = tid >> 2;
    const int lk = (tid & 3) * 4;
    float acc[4][4] = {};
    for (int k0 = 0; k0 < IN; k0 += 16) {
        const float4 av = *(const float4*)&A[(size_t)(m0 + lr) * IN + k0 + lk];
        const float4 bv = *(const float4*)&B[(size_t)(n0 + lr) * IN + k0 + lk];
        __syncthreads();
        As[lr][lk + 0] = av.x; As[lr][lk + 1] = av.y;
        As[lr][lk + 2] = av.z; As[lr][lk + 3] = av.w;
        Bs[lr][lk + 0] = bv.x; Bs[lr][lk + 1] = bv.y;
        Bs[lr][lk + 2] = bv.z; Bs[lr][lk + 3] = bv.w;
        __syncthreads();
#pragma unroll
        for (int k = 0; k < 16; ++k) {
            float a[4], b[4];
#pragma unroll
            for (int i = 0; i < 4; ++i) a[i] = As[ty * 4 + i][k];
#pragma unroll
            for (int j = 0; j < 4; ++j) b[j] = Bs[tx * 4 + j][k];
#pragma unroll
            for (int i = 0; i < 4; ++i)
#pragma unroll
                for (int j = 0; j < 4; ++j) acc[i][j] += a[i] * b[j];
        }
    }
#pragma unroll
    for (int i = 0; i < 4; ++i) {
        float4 v = make_float4(acc[i][0], acc[i][1], acc[i][2], acc[i][3]);
        *(float4*)&out[(size_t)(m0 + ty * 4 + i + 1) * RS + n0 + tx * 4] = v;
    }
}

// fast tanh: 1 - 2/(exp(2x)+1); exact at +/-inf saturation, ~1e-7 rel err.
__device__ __forceinline__ float fast_tanh(float x) {
    float e = __expf(2.0f * x);                      // v_exp_f32 path
    return 1.0f - 2.0f * __builtin_amdgcn_rcpf(e + 1.0f);
}

#define AT_LOAD_U64(p) __hip_atomic_load((p), __ATOMIC_RELAXED, __HIP_MEMORY_SCOPE_AGENT)
#define AT_STORE_U32(p, v) __hip_atomic_store((p), (v), __ATOMIC_RELAXED, __HIP_MEMORY_SCOPE_AGENT)

// ---------------------------------------------------------------------------
// Phase 2: persistent scan, barrier-free dataflow.
// ring: RING rows x RS dwords in d_ws, zeroed at call start. Slot value
// 0x00000000 = "not ready"; state published as bits of (state + 1.0f)
// (state in [-0.0221, 0.0221] -> encoded in [0.978, 1.022], never 0).
// Block b owns rows b*32 .. b*32+31 (wave w: rows b*32+2w, +2w+1).
// Per step t: poll+decode ring[t%8] -> LDS; zero own slice of ring[(t+2)%8];
// dot from W-regs x LDS; tanh; plain-store to out[t+1]; gather 32 encoded
// values in LDS; wave 0 drains vmcnt (orders zero < publish) and publishes
// one coalesced 128B sc1 store into ring[(t+1)%8].
// Skew between blocks is <= 1 step (full-state dependency), so ring reuse at
// distance 8 and pre-zero at distance 2 are race-free (see round journal).
// ---------------------------------------------------------------------------
__global__ __launch_bounds__(BT, 4)
void reservoir_scan_kernel(const float* __restrict__ W_res,
                           const float* __restrict__ init,
                           float* __restrict__ out,
                           unsigned* __restrict__ ring) {
    __shared__ float s_state[RS];
    __shared__ float s_pub[32];
    const int bid  = blockIdx.x;
    const int tid  = threadIdx.x;
    const int wave = tid >> 6;
    const int lane = tid & 63;
    const int r0   = bid * 32 + wave * 2;

    // --- W rows r0, r0+1 into registers; pin against rematerialization ---
    const float* wp0 = W_res + (size_t)r0 * RS + lane * 4;
    const float* wp1 = wp0 + RS;
    float4 w0[8], w1[8];
#pragma unroll
    for (int j = 0; j < 8; ++j) {
        w0[j] = *(const float4*)(wp0 + j * 256);
        w1[j] = *(const float4*)(wp1 + j * 256);
    }
#pragma unroll
    for (int j = 0; j < 8; ++j) {
        asm volatile("" : "+v"(w0[j].x), "+v"(w0[j].y), "+v"(w0[j].z), "+v"(w0[j].w));
        asm volatile("" : "+v"(w1[j].x), "+v"(w1[j].y), "+v"(w1[j].z), "+v"(w1[j].w));
    }

    // --- epoch 0: publish encoded init into ring row 0; out row 0 = init ---
    if (wave == 0 && lane < 32) {
        float v = init[bid * 32 + lane];
        out[bid * 32 + lane] = v;                       // plain store
        AT_STORE_U32(ring + bid * 32 + lane, __float_as_uint(v + 1.0f));
    }

    for (int t = 0; t < SEQ; ++t) {
        const size_t crow = (size_t)(t & (RING - 1)) * RS;
        const size_t prow = (size_t)((t + 1) & (RING - 1)) * RS;
        const size_t zrow = (size_t)((t + 2) & (RING - 1)) * RS;

        // --- preload pre (independent of state t; overlaps the poll) ---
        float pre = 0.f;
        if (lane < 2) pre = out[(size_t)(t + 1) * RS + r0 + lane];

        // --- poll ring row t: each thread owns 2 consecutive dwords ---
        {
            const unsigned long long* pp =
                reinterpret_cast<const unsigned long long*>(ring + crow) + tid;
            unsigned long long v = AT_LOAD_U64(pp);
            while (((unsigned)v == 0u) || ((unsigned)(v >> 32) == 0u))
                v = AT_LOAD_U64(pp);
            s_state[2 * tid]     = __uint_as_float((unsigned)v) - 1.0f;
            s_state[2 * tid + 1] = __uint_as_float((unsigned)(v >> 32)) - 1.0f;
        }
        __syncthreads();

        // --- pre-zero own slice of ring row t+2 (overlaps the dot) ---
        if (wave == 0 && lane < 32)
            AT_STORE_U32(ring + zrow + bid * 32 + lane, 0u);

        // --- dot products: W regs x LDS state ---
        float a0 = 0.f, a1 = 0.f;
#pragma unroll
        for (int j = 0; j < 8; ++j) {
            const float4 sv = *(const float4*)&s_state[lane * 4 + j * 256];
            a0 += w0[j].x * sv.x + w0[j].y * sv.y + w0[j].z * sv.z + w0[j].w * sv.w;
            a1 += w1[j].x * sv.x + w1[j].y * sv.y + w1[j].z * sv.z + w1[j].w * sv.w;
        }
#pragma unroll
        for (int off = 32; off > 0; off >>= 1) {
            a0 += __shfl_xor(a0, off);
            a1 += __shfl_xor(a1, off);
        }

        // --- finish rows r0 (lane 0) and r0+1 (lane 1) in parallel ---
        if (lane < 2) {
            float a = lane ? a1 : a0;
            float s = fast_tanh(pre + a) * INV_SQRT;
            out[(size_t)(t + 1) * RS + r0 + lane] = s;  // plain store
            s_pub[wave * 2 + lane] = s + 1.0f;          // encoded for ring
        }
        __syncthreads();

        // --- publish: one coalesced 128B sc1 store; drain orders zero<pub ---
        if (wave == 0 && lane < 32) {
            asm volatile("s_waitcnt vmcnt(0)" ::: "memory");
            AT_STORE_U32(ring + prow + bid * 32 + lane,
                         __float_as_uint(s_pub[lane]));
        }
    }
}

extern "C" void kernel_launch(void* const* d_in, const int* in_sizes, int n_in,
                              void* d_out, int out_size, void* d_ws, size_t ws_size,
                              hipStream_t stream) {
    const float* x     = (const float*)d_in[0];  // (4096, 512)
    const float* init  = (const float*)d_in[1];  // (2048,)
    const float* W_in  = (const float*)d_in[2];  // (2048, 512)
    const float* W_res = (const float*)d_in[3];  // (2048, 2048)
    float* out = (float*)d_out;                  // (4097, 2048)
    unsigned* ring = (unsigned*)d_ws;

    hipMemsetAsync(d_ws, 0, (size_t)RING * RS * sizeof(float), stream);
    gemm_pre_kernel<<<dim3(SEQ / 64, RS / 64), 256, 0, stream>>>(x, W_in, out);

    void* args[] = { (void*)&W_res, (void*)&init, (void*)&out, (void*)&ring };
    hipLaunchCooperativeKernel((void*)reservoir_scan_kernel,
                               dim3(GB), dim3(BT), args, 0, stream);
}